// Round 11
// baseline (70041.083 us; speedup 1.0000x reference)
//
#include <hip/hip_runtime.h>

#define HN 256
#define QN 64
#define PN 512
#define CH 4

typedef float f4 __attribute__((ext_vector_type(4)));

__device__ __forceinline__ float dot4(f4 a, f4 b) {
  return a.x * b.x + a.y * b.y + a.z * b.z + a.w * b.w;
}
__device__ __forceinline__ float fast_sig(float x) {
  return __builtin_amdgcn_rcpf(1.f + __builtin_amdgcn_exp2f(-1.44269504f * x));
}
__device__ __forceinline__ float fast_tanh(float x) {
  return 1.f - 2.f * __builtin_amdgcn_rcpf(1.f + __builtin_amdgcn_exp2f(2.88539008f * x));
}

struct SMem {
  union {
    float q32[QN][HN];                  // 64KB (prologue only)
    struct {
      alignas(16) float pgc[CH][1024];  // 16KB  bias + Wih[:,0:256] @ p_u
      alignas(16) float wpc[CH][HN];    // 4KB   whp_b + whp_w @ p_u
      alignas(16) float pch[CH][HN];    // 4KB   p rows (f32)
    } c;
  } u;
  alignas(16) float wqt[QN][HN + 4];    // 65KB  wq table (persists all steps)
  alignas(16) float ww[HN];             // w_w staged
  float wrb[HN];                        // whr_b staged
  alignas(16) float biasg[1024];        // 4KB  bih+bhh staged
  alignas(16) float hx[HN];
  float cx[HN];
  alignas(16) float wA[HN];
  alignas(16) float attn[HN];
  float gates[1024];
  float scores[QN];
  alignas(16) float al[QN];
};
static_assert(sizeof(SMem) <= 160 * 1024, "LDS overflow");
static_assert(sizeof(SMem) > 80 * 1024, "want exactly 1 block/CU");

__global__ void __launch_bounds__(1024)
match_kernel(const float* __restrict__ passage, const float* __restrict__ question,
             const float* __restrict__ whq_w, const float* __restrict__ whq_b,
             const float* __restrict__ whp_w, const float* __restrict__ whp_b,
             const float* __restrict__ whr_w, const float* __restrict__ whr_b,
             const float* __restrict__ w_w,
             const float* __restrict__ Wih_f, const float* __restrict__ Whh_f,
             const float* __restrict__ bih_f, const float* __restrict__ bhh_f,
             const float* __restrict__ Wih_b, const float* __restrict__ Whh_b,
             const float* __restrict__ bih_b, const float* __restrict__ bhh_b,
             float* __restrict__ out)
{
  __shared__ SMem sm;
  const int t = threadIdx.x;
  const int bid = blockIdx.x;
  // dir-homogeneous XCD mapping: XCD = bid%8; XCD 0-3 -> dir0, 4-7 -> dir1
  const int e = bid & 7;
  const int dir = e >> 2;
  const int b = ((bid >> 3) << 2) | (e & 3);

  const float* Wih = dir ? Wih_b : Wih_f;
  const float* Whh = dir ? Whh_b : Whh_f;
  const float* bih = dir ? bih_b : bih_f;
  const float* bhh = dir ? bhh_b : bhh_f;

  const int qB = t >> 4;   // 0..63 (phase B q-owner; also row-group base g2)
  const int sg = t & 15;   // 16-lane slice id
  const int g2 = t >> 4;   // row-group base for sliced GEMVs

  // ---------------- prologue 1: stage question[b], init state ----------------
  {
    const int q = t >> 4, c0 = (t & 15) * 16;
    const float* src = question + ((size_t)b * QN + q) * HN + c0;
    #pragma unroll
    for (int m = 0; m < 4; ++m)
      *(f4*)&sm.u.q32[q][c0 + 4 * m] = *(const f4*)(src + 4 * m);
  }
  if (t < HN) {
    sm.hx[t] = 0.f; sm.cx[t] = 0.f;
    sm.wrb[t] = whr_b[t]; sm.ww[t] = w_w[t];
  }
  sm.biasg[t] = bih[t] + bhh[t];
  __syncthreads();

  // ---- prologue 2a: wqt[q][h] = whq_b[h] + sum_k Q[q][k]*whq_w[h][k] ----
  // 1024 threads: h = t&255, group (t>>8) in {0..3} handles 16 q's each.
  {
    const int h = t & 255, qh = (t >> 8) * 16;
    float acc[16];
    const float qb = whq_b[h];
    #pragma unroll
    for (int i2 = 0; i2 < 16; ++i2) acc[i2] = qb;
    const float* wrow = whq_w + (size_t)h * HN;
    for (int k = 0; k < HN; k += 4) {
      f4 w4 = *(const f4*)(wrow + k);
      #pragma unroll
      for (int i2 = 0; i2 < 16; ++i2) {
        f4 qv = *(const f4*)&sm.u.q32[qh + i2][k];
        acc[i2] += dot4(w4, qv);
      }
    }
    #pragma unroll
    for (int i2 = 0; i2 < 16; ++i2) sm.wqt[qh + i2][h] = acc[i2];
  }
  __syncthreads();   // q32 dead; union becomes chunk area

  const int tb = dir ? (PN - 1) : 0;
  const int ts = dir ? -1 : 1;
  const float* qglob = question + (size_t)b * QN * HN;

  for (int s = 0; s < PN; ++s) {
    const int tau = s & (CH - 1);
    if (tau == 0) {
      // ---- stage p chunk (CH=4 rows) ----
      if (t < 256) {
        const int tt = t >> 6, cc = (t & 63) * 4;
        const int trow = tb + ts * (s + tt);
        *(f4*)&sm.u.c.pch[tt][cc] =
            *(const f4*)(passage + ((size_t)b * PN + trow) * HN + cc);
      }
      __syncthreads();
      // ---- wpc[u][h] = whp_b[h] + whp_w[h] . p_u  (rows 256, 4 sliced passes)
      #pragma unroll
      for (int rr = 0; rr < 4; ++rr) {
        const int h = g2 + 64 * rr;
        const float* wrow = whp_w + (size_t)h * HN + sg * 4;
        float acc[CH];
        #pragma unroll
        for (int uu = 0; uu < CH; ++uu) acc[uu] = 0.f;
        #pragma unroll
        for (int m = 0; m < 4; ++m) {
          f4 w = *(const f4*)(wrow + m * 64);
          #pragma unroll
          for (int uu = 0; uu < CH; ++uu)
            acc[uu] += dot4(w, *(const f4*)&sm.u.c.pch[uu][m * 64 + sg * 4]);
        }
        #pragma unroll
        for (int uu = 0; uu < CH; ++uu) {
          acc[uu] += __shfl_xor(acc[uu], 1);
          acc[uu] += __shfl_xor(acc[uu], 2);
          acc[uu] += __shfl_xor(acc[uu], 4);
          acc[uu] += __shfl_xor(acc[uu], 8);
        }
        if (sg == rr) {
          const float pb = whp_b[h];
          #pragma unroll
          for (int uu = 0; uu < CH; ++uu) sm.u.c.wpc[uu][h] = acc[uu] + pb;
        }
      }
      // ---- pgc[u][r] = biasg[r] + Wih[r, 0:256] . p_u  (16 sliced passes) ----
      #pragma unroll
      for (int rr = 0; rr < 16; ++rr) {
        const int r = g2 + 64 * rr;
        const float* wrow = Wih + (size_t)r * 512 + sg * 4;
        float acc[CH];
        #pragma unroll
        for (int uu = 0; uu < CH; ++uu) acc[uu] = 0.f;
        #pragma unroll
        for (int m = 0; m < 4; ++m) {
          f4 w = *(const f4*)(wrow + m * 64);
          #pragma unroll
          for (int uu = 0; uu < CH; ++uu)
            acc[uu] += dot4(w, *(const f4*)&sm.u.c.pch[uu][m * 64 + sg * 4]);
        }
        #pragma unroll
        for (int uu = 0; uu < CH; ++uu) {
          acc[uu] += __shfl_xor(acc[uu], 1);
          acc[uu] += __shfl_xor(acc[uu], 2);
          acc[uu] += __shfl_xor(acc[uu], 4);
          acc[uu] += __shfl_xor(acc[uu], 8);
        }
        if (sg == rr) {
          const float bg = sm.biasg[r];
          #pragma unroll
          for (int uu = 0; uu < CH; ++uu) sm.u.c.pgc[uu][r] = acc[uu] + bg;
        }
      }
      __syncthreads();
    }

    // ---- Phase A: wA[h] = whr_w[h].hx + wpc[tau][h] + whr_b[h] ----
    #pragma unroll
    for (int rr = 0; rr < 4; ++rr) {
      const int h = g2 + 64 * rr;
      const float* wrow = whr_w + (size_t)h * HN + sg * 4;
      float a = 0.f;
      #pragma unroll
      for (int m = 0; m < 4; ++m)
        a += dot4(*(const f4*)(wrow + m * 64),
                  *(const f4*)&sm.hx[m * 64 + sg * 4]);
      a += __shfl_xor(a, 1);
      a += __shfl_xor(a, 2);
      a += __shfl_xor(a, 4);
      a += __shfl_xor(a, 8);
      if (sg == rr) sm.wA[h] = a + sm.u.c.wpc[tau][h] + sm.wrb[h];
    }
    __syncthreads();

    // ---- Phase B: scores[q] = sum_h tanh(wqt[q][h] + wA[h]) * ww[h] ----
    {
      float sc = 0.f;
      #pragma unroll
      for (int jj = 0; jj < 4; ++jj) {
        f4 a4 = *(const f4*)&sm.wA[sg * 16 + 4 * jj];
        f4 q4 = *(const f4*)&sm.wqt[qB][sg * 16 + 4 * jj];
        f4 w4 = *(const f4*)&sm.ww[sg * 16 + 4 * jj];
        sc += fast_tanh(q4.x + a4.x) * w4.x;
        sc += fast_tanh(q4.y + a4.y) * w4.y;
        sc += fast_tanh(q4.z + a4.z) * w4.z;
        sc += fast_tanh(q4.w + a4.w) * w4.w;
      }
      sc += __shfl_xor(sc, 1);
      sc += __shfl_xor(sc, 2);
      sc += __shfl_xor(sc, 4);
      sc += __shfl_xor(sc, 8);
      if (sg == 0) sm.scores[qB] = sc;
    }
    __syncthreads();

    // ---- Phase C: gates[r] = Whh[r].hx (all threads) || softmax (wave 0) ----
    #pragma unroll
    for (int rr = 0; rr < 16; ++rr) {
      const int r = g2 + 64 * rr;
      const float* wrow = Whh + (size_t)r * HN + sg * 4;
      float a = 0.f;
      #pragma unroll
      for (int m = 0; m < 4; ++m)
        a += dot4(*(const f4*)(wrow + m * 64),
                  *(const f4*)&sm.hx[m * 64 + sg * 4]);
      a += __shfl_xor(a, 1);
      a += __shfl_xor(a, 2);
      a += __shfl_xor(a, 4);
      a += __shfl_xor(a, 8);
      if (sg == rr) sm.gates[r] = a;
    }
    if (t < 64) {  // softmax over q; w_b dropped (shift-invariant)
      float sv = sm.scores[t];
      float mx = sv;
      #pragma unroll
      for (int o = 1; o < 64; o <<= 1) mx = fmaxf(mx, __shfl_xor(mx, o));
      float ex = __builtin_amdgcn_exp2f(1.44269504f * (sv - mx));
      float sum = ex;
      #pragma unroll
      for (int o = 1; o < 64; o <<= 1) sum += __shfl_xor(sum, o);
      sm.al[t] = ex * __builtin_amdgcn_rcpf(sum);
    }
    __syncthreads();

    // ---- Phase D: attn[h] = sum_q al[q] * Q[q][h]  (Q from global, L2-hot) ----
    if (t < HN) {
      const float* qcol = qglob + t;
      float a = 0.f;
      #pragma unroll 16
      for (int q = 0; q < QN; ++q)
        a += sm.al[q] * qcol[(size_t)q * HN];
      sm.attn[t] = a;
    }
    __syncthreads();

    // ---- Phase E: gates[r] += Wih[r,256:512].attn + pgc[tau][r] ----
    #pragma unroll
    for (int rr = 0; rr < 16; ++rr) {
      const int r = g2 + 64 * rr;
      const float* wrow = Wih + (size_t)r * 512 + 256 + sg * 4;
      float a = 0.f;
      #pragma unroll
      for (int m = 0; m < 4; ++m)
        a += dot4(*(const f4*)(wrow + m * 64),
                  *(const f4*)&sm.attn[m * 64 + sg * 4]);
      a += __shfl_xor(a, 1);
      a += __shfl_xor(a, 2);
      a += __shfl_xor(a, 4);
      a += __shfl_xor(a, 8);
      if (sg == rr) sm.gates[r] += a + sm.u.c.pgc[tau][r];
    }
    __syncthreads();

    // ---- Phase F: LSTM elementwise + f32 output ----
    if (t < HN) {
      float gi = sm.gates[t], gf = sm.gates[HN + t];
      float gg = sm.gates[2 * HN + t], go = sm.gates[3 * HN + t];
      float c = fast_sig(gf) * sm.cx[t] + fast_sig(gi) * fast_tanh(gg);
      float hn = fast_sig(go) * fast_tanh(c);
      sm.cx[t] = c;
      sm.hx[t] = hn;
      const int trow = tb + ts * s;
      out[((size_t)trow * 64 + b) * 512 + dir * HN + t] = hn;
    }
    __syncthreads();
  }
}

extern "C" void kernel_launch(void* const* d_in, const int* in_sizes, int n_in,
                              void* d_out, int out_size, void* d_ws, size_t ws_size,
                              hipStream_t stream) {
  (void)in_sizes; (void)n_in; (void)out_size; (void)d_ws; (void)ws_size;
  match_kernel<<<dim3(128), dim3(1024), 0, stream>>>(
      (const float*)d_in[0],   // passage
      (const float*)d_in[1],   // question
      (const float*)d_in[2],   // whq_w
      (const float*)d_in[3],   // whq_b
      (const float*)d_in[4],   // whp_w
      (const float*)d_in[5],   // whp_b
      (const float*)d_in[6],   // whr_w
      (const float*)d_in[7],   // whr_b
      (const float*)d_in[8],   // w_w
      (const float*)d_in[10],  // fw_Wih
      (const float*)d_in[11],  // fw_Whh
      (const float*)d_in[12],  // fw_bih
      (const float*)d_in[13],  // fw_bhh
      (const float*)d_in[14],  // bw_Wih
      (const float*)d_in[15],  // bw_Whh
      (const float*)d_in[16],  // bw_bih
      (const float*)d_in[17],  // bw_bhh
      (float*)d_out);
}

// Round 12
// 27175.726 us; speedup vs baseline: 2.5773x; 2.5773x over previous
//
#include <hip/hip_runtime.h>

#define HN 256
#define QN 64
#define PN 512
#define CH 8

typedef float f4 __attribute__((ext_vector_type(4)));

__device__ __forceinline__ float dot4(f4 a, f4 b) {
  return a.x * b.x + a.y * b.y + a.z * b.z + a.w * b.w;
}
__device__ __forceinline__ float fast_sig(float x) {
  return __builtin_amdgcn_rcpf(1.f + __builtin_amdgcn_exp2f(-1.44269504f * x));
}
__device__ __forceinline__ float fast_tanh(float x) {
  return 1.f - 2.f * __builtin_amdgcn_rcpf(1.f + __builtin_amdgcn_exp2f(2.88539008f * x));
}
__device__ __forceinline__ float red16(float v) {
  v += __shfl_xor(v, 1); v += __shfl_xor(v, 2);
  v += __shfl_xor(v, 4); v += __shfl_xor(v, 8);
  return v;
}
__device__ __forceinline__ f4 red16v(f4 v) {
  v.x = red16(v.x); v.y = red16(v.y); v.z = red16(v.z); v.w = red16(v.w);
  return v;
}

struct SMem {
  union {
    float q32[QN][HN];                  // 64KB (prologue only)
    struct {
      alignas(16) float pgc[CH][1024];  // 32KB  Wih[:,0:256] @ p_u
      alignas(16) float wpc[CH][HN];    // 8KB   whp_b + whp_w @ p_u
      alignas(16) float pch[CH][HN];    // 8KB   p rows (f32)
    } c;
  } u;
  alignas(16) float wqt[QN][HN + 4];    // 65KB  wq table (persists all steps)
  alignas(16) float ww[HN];             // w_w staged
  alignas(16) float hx[HN];
  float cx[HN];
  alignas(16) float wA[HN];
  float wrb[HN];                        // whr_b staged
  float gates[1024];
  float scores[QN];
  alignas(16) float al[QN];
};
static_assert(sizeof(SMem) <= 160 * 1024, "LDS overflow");
static_assert(sizeof(SMem) > 80 * 1024, "want exactly 1 block/CU");

// NO per-thread arrays anywhere (allocas defeat promote-alloca -> scratch).
// gq lives in 16 named f4 SSA values; waves_per_eu(1,4) gives a >=128 VGPR budget.
__global__ void
__attribute__((amdgpu_flat_work_group_size(1024, 1024)))
__attribute__((amdgpu_waves_per_eu(1, 4)))
match_kernel(const float* __restrict__ passage, const float* __restrict__ question,
             const float* __restrict__ whq_w, const float* __restrict__ whq_b,
             const float* __restrict__ whp_w, const float* __restrict__ whp_b,
             const float* __restrict__ whr_w, const float* __restrict__ whr_b,
             const float* __restrict__ w_w,
             const float* __restrict__ Wih_f, const float* __restrict__ Whh_f,
             const float* __restrict__ bih_f, const float* __restrict__ bhh_f,
             const float* __restrict__ Wih_b, const float* __restrict__ Whh_b,
             const float* __restrict__ bih_b, const float* __restrict__ bhh_b,
             float* __restrict__ out)
{
  __shared__ SMem sm;
  const int t = threadIdx.x;
  const int bid = blockIdx.x;
  // dir-homogeneous XCD mapping: XCD = bid%8; XCD 0-3 -> dir0, 4-7 -> dir1
  const int e = bid & 7;
  const int dir = e >> 2;
  const int b = ((bid >> 3) << 2) | (e & 3);

  const float* Wih = dir ? Wih_b : Wih_f;
  const float* Whh = dir ? Whh_b : Whh_f;
  const float* bih = dir ? bih_b : bih_f;
  const float* bhh = dir ? bhh_b : bhh_f;

  const int qB = t >> 4;   // 0..63 (phase B q-owner; also row-group base g2)
  const int sg = t & 15;   // 16-lane slice id
  const int g2 = t >> 4;   // row-group base for sliced GEMVs

  // ---------------- prologue 1: stage question[b], init state ----------------
  {
    const int q = t >> 4, c0 = (t & 15) * 16;
    const float* src = question + ((size_t)b * QN + q) * HN + c0;
    #pragma unroll
    for (int m = 0; m < 4; ++m)
      *(f4*)&sm.u.q32[q][c0 + 4 * m] = *(const f4*)(src + 4 * m);
  }
  if (t < HN) {
    sm.hx[t] = 0.f; sm.cx[t] = 0.f;
    sm.wrb[t] = whr_b[t]; sm.ww[t] = w_w[t];
  }
  __syncthreads();

  // ---- prologue 2a: wqt[q][h] = whq_b[h] + sum_k Q[q][k]*whq_w[h][k] ----
  // h = t&255, group (t>>8) in {0..3} handles 16 q's; acc in 4 named f4s.
  {
    const int h = t & 255, qh = (t >> 8) * 16;
    const float qb = whq_b[h];
    f4 ac0, ac1, ac2, ac3;
    ac0.x = ac0.y = ac0.z = ac0.w = qb;
    ac1 = ac0; ac2 = ac0; ac3 = ac0;
    const float* wrow = whq_w + (size_t)h * HN;
    for (int k = 0; k < HN; k += 4) {
      f4 w4 = *(const f4*)(wrow + k);
      #define WQ4(V, Q0) \
        V.x += dot4(w4, *(const f4*)&sm.u.q32[qh + (Q0) + 0][k]); \
        V.y += dot4(w4, *(const f4*)&sm.u.q32[qh + (Q0) + 1][k]); \
        V.z += dot4(w4, *(const f4*)&sm.u.q32[qh + (Q0) + 2][k]); \
        V.w += dot4(w4, *(const f4*)&sm.u.q32[qh + (Q0) + 3][k]);
      WQ4(ac0, 0) WQ4(ac1, 4) WQ4(ac2, 8) WQ4(ac3, 12)
      #undef WQ4
    }
    sm.wqt[qh + 0][h] = ac0.x;  sm.wqt[qh + 1][h] = ac0.y;
    sm.wqt[qh + 2][h] = ac0.z;  sm.wqt[qh + 3][h] = ac0.w;
    sm.wqt[qh + 4][h] = ac1.x;  sm.wqt[qh + 5][h] = ac1.y;
    sm.wqt[qh + 6][h] = ac1.z;  sm.wqt[qh + 7][h] = ac1.w;
    sm.wqt[qh + 8][h] = ac2.x;  sm.wqt[qh + 9][h] = ac2.y;
    sm.wqt[qh + 10][h] = ac2.z; sm.wqt[qh + 11][h] = ac2.w;
    sm.wqt[qh + 12][h] = ac3.x; sm.wqt[qh + 13][h] = ac3.y;
    sm.wqt[qh + 14][h] = ac3.z; sm.wqt[qh + 15][h] = ac3.w;
  }

  // ---- prologue 3: gq[r=t][q] = Wih[r, 256:512].Q[q] -> 16 named f4 ----
  f4 gq00 = {0.f, 0.f, 0.f, 0.f};
  f4 gq01 = gq00, gq02 = gq00, gq03 = gq00, gq04 = gq00, gq05 = gq00,
     gq06 = gq00, gq07 = gq00, gq08 = gq00, gq09 = gq00, gq10 = gq00,
     gq11 = gq00, gq12 = gq00, gq13 = gq00, gq14 = gq00, gq15 = gq00;
  {
    const float* wrow = Wih + (size_t)t * 512 + 256;
    for (int i = 0; i < 64; ++i) {
      f4 w = *(const f4*)(wrow + 4 * i);
      #define GQ4(V, Q0) \
        V.x += dot4(w, *(const f4*)&sm.u.q32[(Q0) + 0][4 * i]); \
        V.y += dot4(w, *(const f4*)&sm.u.q32[(Q0) + 1][4 * i]); \
        V.z += dot4(w, *(const f4*)&sm.u.q32[(Q0) + 2][4 * i]); \
        V.w += dot4(w, *(const f4*)&sm.u.q32[(Q0) + 3][4 * i]);
      GQ4(gq00, 0)  GQ4(gq01, 4)  GQ4(gq02, 8)  GQ4(gq03, 12)
      GQ4(gq04, 16) GQ4(gq05, 20) GQ4(gq06, 24) GQ4(gq07, 28)
      GQ4(gq08, 32) GQ4(gq09, 36) GQ4(gq10, 40) GQ4(gq11, 44)
      GQ4(gq12, 48) GQ4(gq13, 52) GQ4(gq14, 56) GQ4(gq15, 60)
      #undef GQ4
    }
  }
  const float biasr = bih[t] + bhh[t];
  __syncthreads();   // last readers of q32 done; union reused below

  const int tb = dir ? (PN - 1) : 0;
  const int ts = dir ? -1 : 1;

  for (int s = 0; s < PN; ++s) {
    const int tau = s & (CH - 1);
    if (tau == 0) {
      // ---- stage p chunk ----
      if (t < 512) {
        const int tt = t >> 6, cc = (t & 63) * 4;
        const int trow = tb + ts * (s + tt);
        *(f4*)&sm.u.c.pch[tt][cc] =
            *(const f4*)(passage + ((size_t)b * PN + trow) * HN + cc);
      }
      __syncthreads();
      // ---- wpc[u][h] = whp_b[h] + whp_w[h].p_u (4 sliced passes, f4 accs) ----
      #pragma unroll
      for (int rr = 0; rr < 4; ++rr) {
        const int h = g2 + 64 * rr;
        const float* wrow = whp_w + (size_t)h * HN + sg * 4;
        f4 wa0 = {0.f, 0.f, 0.f, 0.f}, wa1 = wa0;
        #pragma unroll
        for (int m = 0; m < 4; ++m) {
          f4 w = *(const f4*)(wrow + m * 64);
          wa0.x += dot4(w, *(const f4*)&sm.u.c.pch[0][m * 64 + sg * 4]);
          wa0.y += dot4(w, *(const f4*)&sm.u.c.pch[1][m * 64 + sg * 4]);
          wa0.z += dot4(w, *(const f4*)&sm.u.c.pch[2][m * 64 + sg * 4]);
          wa0.w += dot4(w, *(const f4*)&sm.u.c.pch[3][m * 64 + sg * 4]);
          wa1.x += dot4(w, *(const f4*)&sm.u.c.pch[4][m * 64 + sg * 4]);
          wa1.y += dot4(w, *(const f4*)&sm.u.c.pch[5][m * 64 + sg * 4]);
          wa1.z += dot4(w, *(const f4*)&sm.u.c.pch[6][m * 64 + sg * 4]);
          wa1.w += dot4(w, *(const f4*)&sm.u.c.pch[7][m * 64 + sg * 4]);
        }
        wa0 = red16v(wa0); wa1 = red16v(wa1);
        if (sg == rr) {
          const float pb = whp_b[h];
          sm.u.c.wpc[0][h] = wa0.x + pb; sm.u.c.wpc[1][h] = wa0.y + pb;
          sm.u.c.wpc[2][h] = wa0.z + pb; sm.u.c.wpc[3][h] = wa0.w + pb;
          sm.u.c.wpc[4][h] = wa1.x + pb; sm.u.c.wpc[5][h] = wa1.y + pb;
          sm.u.c.wpc[6][h] = wa1.z + pb; sm.u.c.wpc[7][h] = wa1.w + pb;
        }
      }
      // ---- pgc[u][r] = Wih[r, 0:256].p_u (16 sliced passes, f4 accs) ----
      #pragma unroll
      for (int rr = 0; rr < 16; ++rr) {
        const int r = g2 + 64 * rr;
        const float* wrow = Wih + (size_t)r * 512 + sg * 4;
        f4 pa0 = {0.f, 0.f, 0.f, 0.f}, pa1 = pa0;
        #pragma unroll
        for (int m = 0; m < 4; ++m) {
          f4 w = *(const f4*)(wrow + m * 64);
          pa0.x += dot4(w, *(const f4*)&sm.u.c.pch[0][m * 64 + sg * 4]);
          pa0.y += dot4(w, *(const f4*)&sm.u.c.pch[1][m * 64 + sg * 4]);
          pa0.z += dot4(w, *(const f4*)&sm.u.c.pch[2][m * 64 + sg * 4]);
          pa0.w += dot4(w, *(const f4*)&sm.u.c.pch[3][m * 64 + sg * 4]);
          pa1.x += dot4(w, *(const f4*)&sm.u.c.pch[4][m * 64 + sg * 4]);
          pa1.y += dot4(w, *(const f4*)&sm.u.c.pch[5][m * 64 + sg * 4]);
          pa1.z += dot4(w, *(const f4*)&sm.u.c.pch[6][m * 64 + sg * 4]);
          pa1.w += dot4(w, *(const f4*)&sm.u.c.pch[7][m * 64 + sg * 4]);
        }
        pa0 = red16v(pa0); pa1 = red16v(pa1);
        if (sg == rr) {
          sm.u.c.pgc[0][r] = pa0.x; sm.u.c.pgc[1][r] = pa0.y;
          sm.u.c.pgc[2][r] = pa0.z; sm.u.c.pgc[3][r] = pa0.w;
          sm.u.c.pgc[4][r] = pa1.x; sm.u.c.pgc[5][r] = pa1.y;
          sm.u.c.pgc[6][r] = pa1.z; sm.u.c.pgc[7][r] = pa1.w;
        }
      }
      __syncthreads();
    }

    // ---- Phase A: wA[h] = whr_w[h].hx + wpc[tau][h] + whr_b[h] ----
    #pragma unroll
    for (int rr = 0; rr < 4; ++rr) {
      const int h = g2 + 64 * rr;
      const float* wrow = whr_w + (size_t)h * HN + sg * 4;
      float a = 0.f;
      #pragma unroll
      for (int m = 0; m < 4; ++m)
        a += dot4(*(const f4*)(wrow + m * 64),
                  *(const f4*)&sm.hx[m * 64 + sg * 4]);
      a = red16(a);
      if (sg == rr) sm.wA[h] = a + sm.u.c.wpc[tau][h] + sm.wrb[h];
    }
    __syncthreads();

    // ---- Phase B: scores[q] = sum_h tanh(wqt[q][h] + wA[h]) * ww[h] ----
    {
      float sc = 0.f;
      #pragma unroll
      for (int jj = 0; jj < 4; ++jj) {
        f4 a4 = *(const f4*)&sm.wA[sg * 16 + 4 * jj];
        f4 q4 = *(const f4*)&sm.wqt[qB][sg * 16 + 4 * jj];
        f4 w4 = *(const f4*)&sm.ww[sg * 16 + 4 * jj];
        sc += fast_tanh(q4.x + a4.x) * w4.x;
        sc += fast_tanh(q4.y + a4.y) * w4.y;
        sc += fast_tanh(q4.z + a4.z) * w4.z;
        sc += fast_tanh(q4.w + a4.w) * w4.w;
      }
      sc = red16(sc);
      if (sg == 0) sm.scores[qB] = sc;
    }
    __syncthreads();

    // ---- Phase C (wave 0 softmax) || Whh[r].hx slice-GEMV (all) ----
    #pragma unroll
    for (int rr = 0; rr < 16; ++rr) {
      const int r = g2 + 64 * rr;
      const float* wrow = Whh + (size_t)r * HN + sg * 4;
      float a = 0.f;
      #pragma unroll
      for (int m = 0; m < 4; ++m)
        a += dot4(*(const f4*)(wrow + m * 64),
                  *(const f4*)&sm.hx[m * 64 + sg * 4]);
      a = red16(a);
      if (sg == rr) sm.gates[r] = a;
    }
    if (t < 64) {  // softmax over q; w_b dropped (shift-invariant)
      float sv = sm.scores[t];
      float mx = sv;
      #pragma unroll
      for (int o = 1; o < 64; o <<= 1) mx = fmaxf(mx, __shfl_xor(mx, o));
      float ex = __builtin_amdgcn_exp2f(1.44269504f * (sv - mx));
      float sum = ex;
      #pragma unroll
      for (int o = 1; o < 64; o <<= 1) sum += __shfl_xor(sum, o);
      sm.al[t] = ex * __builtin_amdgcn_rcpf(sum);
    }
    __syncthreads();

    // ---- Phase E2: gates[r=t] += pgc + bias + Gq[r].alpha (16 dot4) ----
    {
      float acc = sm.gates[t] + sm.u.c.pgc[tau][t] + biasr;
      acc += dot4(gq00, *(const f4*)&sm.al[0]);
      acc += dot4(gq01, *(const f4*)&sm.al[4]);
      acc += dot4(gq02, *(const f4*)&sm.al[8]);
      acc += dot4(gq03, *(const f4*)&sm.al[12]);
      acc += dot4(gq04, *(const f4*)&sm.al[16]);
      acc += dot4(gq05, *(const f4*)&sm.al[20]);
      acc += dot4(gq06, *(const f4*)&sm.al[24]);
      acc += dot4(gq07, *(const f4*)&sm.al[28]);
      acc += dot4(gq08, *(const f4*)&sm.al[32]);
      acc += dot4(gq09, *(const f4*)&sm.al[36]);
      acc += dot4(gq10, *(const f4*)&sm.al[40]);
      acc += dot4(gq11, *(const f4*)&sm.al[44]);
      acc += dot4(gq12, *(const f4*)&sm.al[48]);
      acc += dot4(gq13, *(const f4*)&sm.al[52]);
      acc += dot4(gq14, *(const f4*)&sm.al[56]);
      acc += dot4(gq15, *(const f4*)&sm.al[60]);
      sm.gates[t] = acc;
    }
    __syncthreads();

    // ---- Phase F: LSTM elementwise + f32 output ----
    if (t < HN) {
      float gi = sm.gates[t], gf = sm.gates[HN + t];
      float gg = sm.gates[2 * HN + t], go = sm.gates[3 * HN + t];
      float c = fast_sig(gf) * sm.cx[t] + fast_sig(gi) * fast_tanh(gg);
      float hn = fast_sig(go) * fast_tanh(c);
      sm.cx[t] = c;
      sm.hx[t] = hn;
      const int trow = tb + ts * s;
      out[((size_t)trow * 64 + b) * 512 + dir * HN + t] = hn;
    }
    __syncthreads();
  }
}

extern "C" void kernel_launch(void* const* d_in, const int* in_sizes, int n_in,
                              void* d_out, int out_size, void* d_ws, size_t ws_size,
                              hipStream_t stream) {
  (void)in_sizes; (void)n_in; (void)out_size; (void)d_ws; (void)ws_size;
  match_kernel<<<dim3(128), dim3(1024), 0, stream>>>(
      (const float*)d_in[0],   // passage
      (const float*)d_in[1],   // question
      (const float*)d_in[2],   // whq_w
      (const float*)d_in[3],   // whq_b
      (const float*)d_in[4],   // whp_w
      (const float*)d_in[5],   // whp_b
      (const float*)d_in[6],   // whr_w
      (const float*)d_in[7],   // whr_b
      (const float*)d_in[8],   // w_w
      (const float*)d_in[10],  // fw_Wih
      (const float*)d_in[11],  // fw_Whh
      (const float*)d_in[12],  // fw_bih
      (const float*)d_in[13],  // fw_bhh
      (const float*)d_in[14],  // bw_Wih
      (const float*)d_in[15],  // bw_Whh
      (const float*)d_in[16],  // bw_bih
      (const float*)d_in[17],  // bw_bhh
      (float*)d_out);
}